// Round 4
// baseline (419.338 us; speedup 1.0000x reference)
//
#include <hip/hip_runtime.h>

#define EMBED_D  2048
#define N_EXP    64
#define K_TOP    8
#define TOK_BLK  64
#define THREADS  256
#define NCHUNK   64             // K chunks of 32
#define WCHUNK_B 12288          // W-frag bytes/chunk: 3 planes * 4 n * 64 lanes * 16
#define XCHUNK_B 8192           // X bytes/chunk: 64 tok * 32 k * 4
#define BUF_B    (WCHUNK_B + XCHUNK_B)   // 20480

typedef __attribute__((ext_vector_type(8))) short bf16x8;   // 8 bf16 = 4 VGPR
typedef __attribute__((ext_vector_type(4))) float f32x4;    // MFMA C/D

__device__ __forceinline__ uint bf16_rne(float x) {
    uint u = __float_as_uint(x);
    return (u + 0x7fffu + ((u >> 16) & 1u)) >> 16;
}
__device__ __forceinline__ float bf16f(uint h) { return __uint_as_float(h << 16); }

// direct global->LDS, 16 B per lane; LDS dest = wave-uniform base + lane*16
__device__ __forceinline__ void stage16(const void* g, void* l)
{
    typedef __attribute__((address_space(1))) const unsigned int gu32;
    typedef __attribute__((address_space(3))) unsigned int lu32;
    __builtin_amdgcn_global_load_lds((gu32*)g, (lu32*)l, 16, 0, 0);
}

// x[8] -> h/m/l bf16x8 fragments. h,m: RNE (bit-identical to R3); l: trunc.
// Pack via v_perm_b32: ~9.5 VALU ops/elem vs 16 for the shift-based version.
__device__ __forceinline__ void split3(float4 u, float4 v, bf16x8& H, bf16x8& M, bf16x8& L)
{
    const float x[8] = {u.x, u.y, u.z, u.w, v.x, v.y, v.z, v.w};
    uint hw[8], mw[8], lw[8];
#pragma unroll
    for (int j = 0; j < 8; ++j) {
        const uint ux = __float_as_uint(x[j]);
        hw[j] = (ux + 0x7fffu + ((ux >> 16) & 1u)) & 0xffff0000u;   // RNE, low16 zero
        const float r1 = x[j] - __uint_as_float(hw[j]);             // exact
        const uint ur = __float_as_uint(r1);
        mw[j] = (ur + 0x7fffu + ((ur >> 16) & 1u)) & 0xffff0000u;   // RNE
        lw[j] = __float_as_uint(r1 - __uint_as_float(mw[j]));       // trunc via pack
    }
    uint* hp = (uint*)&H; uint* mp = (uint*)&M; uint* lp = (uint*)&L;
#pragma unroll
    for (int w = 0; w < 4; ++w) {   // word = hi16(odd)<<16 | hi16(even)
        hp[w] = __builtin_amdgcn_perm(hw[2 * w + 1], hw[2 * w], 0x07060302u);
        mp[w] = __builtin_amdgcn_perm(mw[2 * w + 1], mw[2 * w], 0x07060302u);
        lp[w] = __builtin_amdgcn_perm(lw[2 * w + 1], lw[2 * w], 0x07060302u);
    }
}

// W[64][2048] fp32 -> fragment-major h/m/l planes, K32-chunk layout.
// Byte layout: chunk c | (p*4+n)*1024 | lane*16 | j*2
// expert e = n*16+row, k = c*32+g*8+j, lane = g*16+row.
__global__ void w_prep(const float* __restrict__ W, ushort* __restrict__ WF)
{
    const int e = blockIdx.x;       // expert 0..63
    const int t = threadIdx.x;      // 0..255, 8 consecutive k each
    const float4 a = *(const float4*)(W + (size_t)e * EMBED_D + t * 8);
    const float4 b = *(const float4*)(W + (size_t)e * EMBED_D + t * 8 + 4);
    const float ev[8] = {a.x, a.y, a.z, a.w, b.x, b.y, b.z, b.w};
    ushort h[8], m[8], l[8];
#pragma unroll
    for (int j = 0; j < 8; ++j) {
        const uint hh = bf16_rne(ev[j]);
        const float r1 = ev[j] - bf16f(hh);
        const uint mm = bf16_rne(r1);
        const uint ll = bf16_rne(r1 - bf16f(mm));
        h[j] = (ushort)hh; m[j] = (ushort)mm; l[j] = (ushort)ll;
    }
    const int c = t >> 2;           // K32 chunk
    const int g = t & 3;
    const int lane = g * 16 + (e & 15);
    const int n    = e >> 4;
    // ushort offsets: c*6144 + p*2048 + n*512 + lane*8
    const size_t base = (size_t)c * 6144 + (size_t)n * 512 + (size_t)lane * 8;
    ushort4* H = (ushort4*)(WF + base);
    ushort4* M = (ushort4*)(WF + base + 2048);
    ushort4* L = (ushort4*)(WF + base + 4096);
    H[0] = make_ushort4(h[0], h[1], h[2], h[3]); H[1] = make_ushort4(h[4], h[5], h[6], h[7]);
    M[0] = make_ushort4(m[0], m[1], m[2], m[3]); M[1] = make_ushort4(m[4], m[5], m[6], m[7]);
    L[0] = make_ushort4(l[0], l[1], l[2], l[3]); L[1] = make_ushort4(l[4], l[5], l[6], l[7]);
}

__global__ __launch_bounds__(THREADS, 4) void moe_gate_main(
    const float*  __restrict__ X,    // [n_tok][2048] fp32
    const ushort* __restrict__ WF,   // fragment-major W planes (768 KB)
    float* __restrict__ out,
    float* __restrict__ ws,
    int n_tok)
{
    // double-buffered {W 12K | X 8K}; reused as Lp after the loop
    __shared__ __align__(16) char smem[2 * BUF_B];   // 40960 B
    __shared__ float sInvZ[TOK_BLK];
    __shared__ float sCnt[N_EXP];
    __shared__ float sColp[4][N_EXP];

    const int tid  = threadIdx.x;
    const int lane = tid & 63;
    const int wv   = __builtin_amdgcn_readfirstlane(tid >> 6);  // 0..3
    const int tg   = wv & 1;      // token half (32 tokens)
    const int eh   = wv >> 1;     // expert half (32 experts)
    const int row  = lane & 15;
    const int g    = lane >> 4;
    const int t0   = blockIdx.x * TOK_BLK;

    // ---- staging sources (advance 1 chunk/iter) ----
    const char* wsrc = (const char*)WF + (size_t)wv * 1024 + lane * 16;
    // X slot qi = r*256 + wv*64 + lane -> tok = qi>>3, phys q = qi&7,
    // logical q = phys ^ (tok&7)  (XOR swizzle; LDS dest stays linear)
    const float* xsrc0; const float* xsrc1;
    {
        const int q0 = wv * 64 + lane,       t0k = q0 >> 3;
        const int q1 = 256 + wv * 64 + lane, t1k = q1 >> 3;
        xsrc0 = X + (size_t)(t0 + t0k) * EMBED_D + ((q0 & 7) ^ (t0k & 7)) * 4;
        xsrc1 = X + (size_t)(t0 + t1k) * EMBED_D + ((q1 & 7) ^ (t1k & 7)) * 4;
    }

    // ---- X read offsets in Xbuf (bytes): token tk, logical quarters 2g,2g+1 ----
    int xo[2][2];
#pragma unroll
    for (int ai = 0; ai < 2; ++ai) {
        const int tk = tg * 32 + ai * 16 + row;
        const int s  = tk & 7;
        xo[ai][0] = tk * 128 + ((2 * g)     ^ s) * 16;
        xo[ai][1] = tk * 128 + ((2 * g + 1) ^ s) * 16;
    }

    f32x4 acc[2][2];
#pragma unroll
    for (int ai = 0; ai < 2; ++ai)
#pragma unroll
        for (int nl = 0; nl < 2; ++nl)
            acc[ai][nl] = (f32x4){0.f, 0.f, 0.f, 0.f};

    // stage chunk 0 into buffer 0
    {
        char* bb = smem;
#pragma unroll
        for (int r = 0; r < 3; ++r)
            stage16(wsrc + r * 4096, bb + r * 4096 + wv * 1024);
        stage16(xsrc0, bb + WCHUNK_B + wv * 1024);
        stage16(xsrc1, bb + WCHUNK_B + 4096 + wv * 1024);
    }
    __syncthreads();   // vmcnt(0) drain: chunk 0 staged

    for (int c = 0; c < NCHUNK; ++c) {
        const int cur = c & 1;

        // (1) fire-and-forget staging of next chunk (drained by this iter's barrier)
        if (c + 1 < NCHUNK) {
            char* bb = smem + (cur ^ 1) * BUF_B;
            const char* wsc = wsrc + (size_t)(c + 1) * WCHUNK_B;
#pragma unroll
            for (int r = 0; r < 3; ++r)
                stage16(wsc + r * 4096, bb + r * 4096 + wv * 1024);
            stage16(xsrc0 + (c + 1) * 32, bb + WCHUNK_B + wv * 1024);
            stage16(xsrc1 + (c + 1) * 32, bb + WCHUNK_B + 4096 + wv * 1024);
        }

        const char* bb = smem + cur * BUF_B;
        const char* xb = bb + WCHUNK_B;

        // (2) A fragments: X from LDS, split h/m/l
        bf16x8 ah[2], am[2], al[2];
#pragma unroll
        for (int ai = 0; ai < 2; ++ai) {
            const float4 u = *(const float4*)(xb + xo[ai][0]);
            const float4 v = *(const float4*)(xb + xo[ai][1]);
            split3(u, v, ah[ai], am[ai], al[ai]);
        }

        // (3) B fragments + MFMA (contiguous lane*16 ds_read_b128, conflict-free)
#pragma unroll
        for (int nl = 0; nl < 2; ++nl) {
            const int n = eh * 2 + nl;
            const char* bp = bb + (size_t)n * 1024 + lane * 16;
            const bf16x8 bh = *(const bf16x8*)(bp);
            const bf16x8 bm = *(const bf16x8*)(bp + 4096);
            const bf16x8 bl = *(const bf16x8*)(bp + 8192);
#pragma unroll
            for (int ai = 0; ai < 2; ++ai) {
                acc[ai][nl] = __builtin_amdgcn_mfma_f32_16x16x32_bf16(ah[ai], bh, acc[ai][nl], 0, 0, 0);
                acc[ai][nl] = __builtin_amdgcn_mfma_f32_16x16x32_bf16(am[ai], bh, acc[ai][nl], 0, 0, 0);
                acc[ai][nl] = __builtin_amdgcn_mfma_f32_16x16x32_bf16(ah[ai], bm, acc[ai][nl], 0, 0, 0);
                acc[ai][nl] = __builtin_amdgcn_mfma_f32_16x16x32_bf16(al[ai], bh, acc[ai][nl], 0, 0, 0);
                acc[ai][nl] = __builtin_amdgcn_mfma_f32_16x16x32_bf16(ah[ai], bl, acc[ai][nl], 0, 0, 0);
                acc[ai][nl] = __builtin_amdgcn_mfma_f32_16x16x32_bf16(am[ai], bm, acc[ai][nl], 0, 0, 0);
            }
        }
        __syncthreads();   // compute done + next chunk staged (vmcnt0 drain)
    }

    // buffers dead -> reuse smem as logits [tok][exp], stride 65
    float (*Lp)[N_EXP + 1] = (float (*)[N_EXP + 1])smem;
    // C/D layout: col = lane&15 (expert-in-16), row = g*4 + reg (token-in-16)
#pragma unroll
    for (int ai = 0; ai < 2; ++ai)
#pragma unroll
        for (int nl = 0; nl < 2; ++nl)
#pragma unroll
            for (int r = 0; r < 4; ++r)
                Lp[tg * 32 + ai * 16 + g * 4 + r][(eh * 2 + nl) * 16 + row] = acc[ai][nl][r];
    if (tid < N_EXP) sCnt[tid] = 0.f;
    __syncthreads();

    // per-token softmax + top-8 (threads 0..63)
    if (tid < TOK_BLK) {
        const int t = tid;
        float mx = -1e30f;
        for (int e = 0; e < N_EXP; ++e)
            mx = fmaxf(mx, Lp[t][e]);
        float Z = 0.f;
        float tv[K_TOP]; int ti[K_TOP];
#pragma unroll
        for (int j = 0; j < K_TOP; ++j) { tv[j] = -1e30f; ti[j] = 0; }
        for (int e = 0; e < N_EXP; ++e) {
            const float s = __expf(Lp[t][e] - mx);
            Lp[t][e] = s;                 // unnormalized score for Pi pass
            Z += s;
            float v = s; int id = e;
#pragma unroll
            for (int j = 0; j < K_TOP; ++j) {  // strict > : ties keep lower idx
                if (v > tv[j]) {
                    float fv = tv[j]; tv[j] = v; v = fv;
                    int   fi = ti[j]; ti[j] = id; id = fi;
                }
            }
        }
        const float invZ = 1.0f / Z;
        sInvZ[t] = invZ;
        const size_t ob = (size_t)(t0 + t) * K_TOP;
        const size_t wo = (size_t)n_tok * K_TOP;
#pragma unroll
        for (int j = 0; j < K_TOP; ++j) {
            out[ob + j]      = (float)ti[j];
            out[wo + ob + j] = tv[j] * invZ;
            atomicAdd(&sCnt[ti[j]], 1.0f);
        }
    }
    __syncthreads();

    // per-expert score sums (Pi numerator): 4 groups x 16 tokens
    {
        const int e = tid & 63, g2 = tid >> 6;
        float s = 0.f;
#pragma unroll
        for (int i = 0; i < 16; ++i) {
            const int t = g2 * 16 + i;
            s += Lp[t][e] * sInvZ[t];
        }
        sColp[g2][e] = s;
    }
    __syncthreads();
    if (tid < N_EXP) {
        float s = 0.f;
#pragma unroll
        for (int g2 = 0; g2 < 4; ++g2) s += sColp[g2][tid];
        atomicAdd(&ws[64 + tid], s);
        atomicAdd(&ws[tid], sCnt[tid]);
    }
}

__global__ void moe_aux(const float* __restrict__ ws, float* __restrict__ out, int n_tok)
{
    const int e = threadIdx.x;   // 64 threads
    const float counts = ws[e];
    const float ssum   = ws[64 + e];
    const float Pi = ssum / (float)n_tok;
    const float ce = counts / ((float)n_tok * (float)K_TOP);
    float term = Pi * ce * (float)N_EXP;
    for (int off = 32; off; off >>= 1) term += __shfl_down(term, off);
    if (e == 0) out[(size_t)2 * n_tok * K_TOP] = term * 0.01f;
}

extern "C" void kernel_launch(void* const* d_in, const int* in_sizes, int n_in,
                              void* d_out, int out_size, void* d_ws, size_t ws_size,
                              hipStream_t stream)
{
    const float* X = (const float*)d_in[0];
    const float* W = (const float*)d_in[1];
    float* out = (float*)d_out;
    float* ws  = (float*)d_ws;
    const int n_tok = in_sizes[0] / EMBED_D;   // 32768

    // workspace: [0..255] floats counters | fragment-major W planes (768 KB)
    ushort* WF = (ushort*)(ws + 256);

    hipMemsetAsync(ws, 0, 2 * N_EXP * sizeof(float), stream);
    w_prep<<<N_EXP, 256, 0, stream>>>(W, WF);
    moe_gate_main<<<n_tok / TOK_BLK, THREADS, 0, stream>>>(X, WF, out, ws, n_tok);
    moe_aux<<<1, 64, 0, stream>>>(ws, out, n_tok);
}